// Round 6
// baseline (234.355 us; speedup 1.0000x reference)
//
#include <hip/hip_runtime.h>
#include <math.h>

// SPGG Fermi update, L=4096 periodic lattice — register-streaming v2.
// Changes vs v1 (which was latency-bound: occ 24%, VALU 19%, HBM 23%):
//   - BANDH 16->8  => 2304 blocks, 9216 waves (2x TLP)
//   - 2 output rows per iteration => 6 loads in flight per wave (2x MLP)
//   - nontemporal lp/dir loads + out stores (preserve L2 for t halo)
//   - bijective XCD swizzle so adjacent bands share halo rows in one L2
// f32 op order identical to the verified absmax-0.0 kernels.

#define LSZ 4096
#define LMASK 4095
#define STRIPS 18        // 18 * 232 = 4176 >= 4096 (overlaps write identical values)
#define OUTW 232         // valid output cols per strip (lanes 3..60)
#define BANDH 8          // rows per wave

typedef float v4f __attribute__((ext_vector_type(4)));
typedef int   v4i __attribute__((ext_vector_type(4)));

__device__ __forceinline__ v4f a_row(v4f tm, v4f tc, v4f tp,
                                     int lm1, int lp1, float& tl, float& tr) {
    tl = __shfl(tc.w, lm1);
    tr = __shfl(tc.x, lp1);
    v4f n, a;
    // reference order: ((((center + up) + down) + left) + right)
    n.x = (((tc.x + tm.x) + tp.x) + tl)   + tc.y;
    n.y = (((tc.y + tm.y) + tp.y) + tc.x) + tc.z;
    n.z = (((tc.z + tm.z) + tp.z) + tc.y) + tc.w;
    n.w = (((tc.w + tm.w) + tp.w) + tc.z) + tr;
    // n*0.2f*3.0f bit-identical to n/5.0f*3.0f for n in {0..5}
    a.x = n.x * 0.2f * 3.0f;
    a.y = n.y * 0.2f * 3.0f;
    a.z = n.z * 0.2f * 3.0f;
    a.w = n.w * 0.2f * 3.0f;
    return a;
}

__device__ __forceinline__ v4f p_row(v4f am, v4f ac, v4f ap, v4f tc,
                                     int lm1, int lp1) {
    float al = __shfl(ac.w, lm1);
    float ar = __shfl(ac.x, lp1);
    v4f p;
    {
        float d5 = (((ac.x + am.x) + ap.x) + al) + ac.y;
        float c5 = ((((ac.x - 1.0f) + (am.x - 1.0f)) + (ap.x - 1.0f)) + (al - 1.0f)) + (ac.y - 1.0f);
        p.x = (tc.x == 1.0f) ? c5 : d5;
    }
    {
        float d5 = (((ac.y + am.y) + ap.y) + ac.x) + ac.z;
        float c5 = ((((ac.y - 1.0f) + (am.y - 1.0f)) + (ap.y - 1.0f)) + (ac.x - 1.0f)) + (ac.z - 1.0f);
        p.y = (tc.y == 1.0f) ? c5 : d5;
    }
    {
        float d5 = (((ac.z + am.z) + ap.z) + ac.y) + ac.w;
        float c5 = ((((ac.z - 1.0f) + (am.z - 1.0f)) + (ap.z - 1.0f)) + (ac.y - 1.0f)) + (ac.w - 1.0f);
        p.z = (tc.z == 1.0f) ? c5 : d5;
    }
    {
        float d5 = (((ac.w + am.w) + ap.w) + ac.z) + ar;
        float c5 = ((((ac.w - 1.0f) + (am.w - 1.0f)) + (ap.w - 1.0f)) + (ac.z - 1.0f)) + (ar - 1.0f);
        p.w = (tc.w == 1.0f) ? c5 : d5;
    }
    return p;
}

__device__ __forceinline__ float fermi(float pc, float pnl, float pnr, float pnu, float pnd,
                                       float tc, float tnl, float tnr, float tnu, float tnd,
                                       float lpx, int k) {
    float pn = (k == 0) ? pnl : (k == 1) ? pnr : (k == 2) ? pnu : pnd;
    float tn = (k == 0) ? tnl : (k == 1) ? tnr : (k == 2) ? tnu : tnd;
    float d  = pc - pn;
    // fast path (rel err ~1e-5) with conservative uncertainty band
    float ef = __expf(d * 10.0f);
    float Wf = __builtin_amdgcn_rcpf(1.0f + ef);
    float eps = 1e-4f * Wf + 1e-37f;
    float res;
    if (lpx <= Wf - eps)      res = tn;
    else if (lpx > Wf + eps)  res = tc;
    else {
        // bit-exact reference path (verified absmax 0.0 in rounds 1-2-5)
        float arg = d / 0.1f;
        float e = (float)exp((double)arg);
        float W = 1.0f / (1.0f + e);
        res = (lpx <= W) ? tn : tc;
    }
    return res;
}

__global__ __launch_bounds__(256, 4) void spgg_fermi_kernel(
    const float* __restrict__ t,       // type matrix, 0.0/1.0
    const float* __restrict__ lp,      // learning probabilities
    const int*   __restrict__ dir,     // learning direction 0..3
    float* __restrict__ out)
{
    const int lane = threadIdx.x & 63;
    const int wv   = threadIdx.x >> 6;

    // bijective XCD swizzle: nwg = 2304 = 8 * 288
    const int orig = blockIdx.x;
    const int e    = (orig & 7) * 288 + (orig >> 3);
    const int s    = e >> 7;                   // strip 0..17
    const int bg   = e & 127;                  // 0..127
    const int band = bg * 4 + wv;              // 0..511
    const int r0   = band * BANDH;
    const int cb   = s * OUTW - 12;            // lane-0 col of this strip
    const int col  = (cb + 4 * lane) & LMASK;  // 16B-aligned, wrapped
    const int lm1  = (lane + 63) & 63;
    const int lp1  = (lane + 1) & 63;
    const bool valid = (lane >= 3) && (lane <= 60);

    auto ldT  = [&](int r_) -> v4f { return *(const v4f*)&t[((r_ & LMASK) << 12) + col]; };
    auto ldLP = [&](int r_) -> v4f {
        return __builtin_nontemporal_load((const v4f*)&lp[((r_ & LMASK) << 12) + col]);
    };
    auto ldDR = [&](int r_) -> v4i {
        return __builtin_nontemporal_load((const v4i*)&dir[((r_ & LMASK) << 12) + col]);
    };

    // ---- warmup: fill pipeline for output row r0 ----
    v4f u0 = ldT(r0 - 3), u1 = ldT(r0 - 2), u2 = ldT(r0 - 1), u3 = ldT(r0);
    v4f u4 = ldT(r0 + 1), u5 = ldT(r0 + 2), u6 = ldT(r0 + 3);
    v4f LPc = ldLP(r0);
    v4i DRc = ldDR(r0);

    float tlA, trA, tlB, trB, tlC, trC, tlD, trD, ts0, ts1;
    v4f aM2 = a_row(u0, u1, u2, lm1, lp1, ts0, ts1);     // a(r0-2)
    v4f aM1 = a_row(u1, u2, u3, lm1, lp1, ts0, ts1);     // a(r0-1)
    v4f A0  = a_row(u2, u3, u4, lm1, lp1, tlA, trA);     // a(r0),   t-edges row r0
    v4f A1  = a_row(u3, u4, u5, lm1, lp1, tlB, trB);     // a(r0+1), t-edges row r0+1
    v4f P0  = p_row(aM2, aM1, A0, u2, lm1, lp1);         // p(r0-1)
    v4f P1  = p_row(aM1, A0, A1, u3, lm1, lp1);          // p(r0)

    v4f T0 = u2, T1 = u3, T2 = u4, T3 = u5, T4 = u6;     // t(r-1 .. r+3)

    // ---- main loop: TWO output rows per iteration (6 loads in flight) ----
    #pragma unroll 2
    for (int ii = 0; ii < BANDH; ii += 2) {
        const int r = r0 + ii;

        v4f Tn4 = ldT(r + 4);
        v4f Tn5 = ldT(r + 5);
        v4f LP1 = ldLP(r + 1);
        v4f LP2 = ldLP(r + 2);
        v4i DR1 = ldDR(r + 1);
        v4i DR2 = ldDR(r + 2);

        v4f A2 = a_row(T2, T3, T4,  lm1, lp1, tlC, trC);  // a(r+2), t-edges row r+2
        v4f A3 = a_row(T3, T4, Tn4, lm1, lp1, tlD, trD);  // a(r+3), t-edges row r+3
        v4f P2 = p_row(A0, A1, A2, T2, lm1, lp1);         // p(r+1)
        v4f P3 = p_row(A1, A2, A3, T3, lm1, lp1);         // p(r+2)

        // ---- output row r ----
        {
            float plx = __shfl(P1.w, lm1);
            float prx = __shfl(P1.x, lp1);
            v4f o;
            o.x = fermi(P1.x, plx,  P1.y, P0.x, P2.x, T1.x, tlA,  T1.y, T0.x, T2.x, LPc.x, DRc.x);
            o.y = fermi(P1.y, P1.x, P1.z, P0.y, P2.y, T1.y, T1.x, T1.z, T0.y, T2.y, LPc.y, DRc.y);
            o.z = fermi(P1.z, P1.y, P1.w, P0.z, P2.z, T1.z, T1.y, T1.w, T0.z, T2.z, LPc.z, DRc.z);
            o.w = fermi(P1.w, P1.z, prx,  P0.w, P2.w, T1.w, T1.z, trA,  T0.w, T2.w, LPc.w, DRc.w);
            if (valid)
                __builtin_nontemporal_store(o, (v4f*)&out[(r << 12) + col]);
        }

        // ---- output row r+1 ----
        {
            float plx = __shfl(P2.w, lm1);
            float prx = __shfl(P2.x, lp1);
            v4f o;
            o.x = fermi(P2.x, plx,  P2.y, P1.x, P3.x, T2.x, tlB,  T2.y, T1.x, T3.x, LP1.x, DR1.x);
            o.y = fermi(P2.y, P2.x, P2.z, P1.y, P3.y, T2.y, T2.x, T2.z, T1.y, T3.y, LP1.y, DR1.y);
            o.z = fermi(P2.z, P2.y, P2.w, P1.z, P3.z, T2.z, T2.y, T2.w, T1.z, T3.z, LP1.z, DR1.z);
            o.w = fermi(P2.w, P2.z, prx,  P1.w, P3.w, T2.w, T2.z, trB,  T1.w, T3.w, LP1.w, DR1.w);
            if (valid)
                __builtin_nontemporal_store(o, (v4f*)&out[((r + 1) << 12) + col]);
        }

        // ---- rotate pipeline state by 2 rows ----
        T0 = T2; T1 = T3; T2 = T4; T3 = Tn4; T4 = Tn5;
        A0 = A2; A1 = A3;
        P0 = P2; P1 = P3;
        tlA = tlC; trA = trC; tlB = tlD; trB = trD;
        LPc = LP2; DRc = DR2;
    }
}

extern "C" void kernel_launch(void* const* d_in, const int* in_sizes, int n_in,
                              void* d_out, int out_size, void* d_ws, size_t ws_size,
                              hipStream_t stream)
{
    const float* t   = (const float*)d_in[0];
    const float* lp  = (const float*)d_in[1];
    const int*   dir = (const int*)d_in[2];
    float* out = (float*)d_out;

    // 18 strips x 128 block-groups (4 waves/block = 4 bands of 8 rows)
    dim3 grid(STRIPS * 128);   // 2304 blocks
    dim3 block(256);
    hipLaunchKernelGGL(spgg_fermi_kernel, grid, block, 0, stream, t, lp, dir, out);
}